// Round 2
// baseline (7100.800 us; speedup 1.0000x reference)
//
#include <hip/hip_runtime.h>
#include <hip/hip_bf16.h>
#include <math.h>

#define DIM 512
#define NHEAD 8
#define HD 64
#define BATCH 2
#define SEQ 4096
#define CTXLEN 77
#define NTOK (BATCH*SEQ)     // 8192
#define NCTX (BATCH*CTXLEN)  // 154

typedef __hip_bfloat16 bf16;

__device__ __forceinline__ float b2f(bf16 v){ return __bfloat162float(v); }
__device__ __forceinline__ bf16  f2b(float v){ return __float2bfloat16(v); }
__device__ __forceinline__ float toF(float v){ return v; }
__device__ __forceinline__ float toF(bf16 v){ return __bfloat162float(v); }
__device__ __forceinline__ void  stf(float* p, float v){ *p = v; }
__device__ __forceinline__ void  stf(bf16* p, float v){ *p = f2b(v); }

// ---------------- LayerNorm: one wave per row of 512; fp32 in, bf16 out ----------------
__global__ __launch_bounds__(256)
void ln_kernel(const float* __restrict__ x, const float* __restrict__ g,
               const float* __restrict__ b, bf16* __restrict__ out, int nrows)
{
    int row  = blockIdx.x * 4 + (threadIdx.x >> 6);
    int lane = threadIdx.x & 63;
    if (row >= nrows) return;
    const float* xr = x + (size_t)row * DIM;
    float v[8];
    float s = 0.f, sq = 0.f;
    #pragma unroll
    for (int j = 0; j < 8; ++j) {
        float f = xr[lane + 64*j];
        v[j] = f; s += f; sq += f*f;
    }
    #pragma unroll
    for (int off = 32; off; off >>= 1) {
        s  += __shfl_xor(s,  off);
        sq += __shfl_xor(sq, off);
    }
    float mean = s * (1.f/DIM);
    float var  = sq * (1.f/DIM) - mean*mean;
    float rstd = rsqrtf(var + 1e-5f);
    bf16* orow = out + (size_t)row * DIM;
    #pragma unroll
    for (int j = 0; j < 8; ++j) {
        int c = lane + 64*j;
        orow[c] = f2b((v[j]-mean)*rstd*g[c] + b[c]);
    }
}

// ---------------- GEMM: C = A[MxK] @ W[KxN] (+bias)(+resid fp32) ----------------
// 128x128 tile, BK=32, 8x8 micro-tile, 256 threads.
template<typename AT, int RESID, typename OUTT>
__global__ __launch_bounds__(256)
void gemm_kernel(const AT* __restrict__ A, const float* __restrict__ W,
                 const float* __restrict__ bias, const float* __restrict__ resid,
                 OUTT* __restrict__ outp, int M, int N, int K)
{
    __shared__ __align__(16) float As[32][132];  // transposed: [k][m]
    __shared__ __align__(16) float Bs[32][132];  // [k][n]
    const int tid = threadIdx.x;
    const int tx = tid & 15, ty = tid >> 4;
    const int n0 = blockIdx.x * 128, m0 = blockIdx.y * 128;
    float acc[8][8] = {};
    for (int k0 = 0; k0 < K; k0 += 32) {
        {
            int kk = tid & 31, r0 = tid >> 5;
            #pragma unroll
            for (int p = 0; p < 16; ++p) {
                int r = r0 + p*8;
                int row = m0 + r;
                As[kk][r] = (row < M) ? toF(A[(size_t)row*K + k0 + kk]) : 0.f;
            }
            int c = tid & 127, kw0 = tid >> 7;
            #pragma unroll
            for (int p = 0; p < 16; ++p) {
                int kw = kw0 + p*2;
                Bs[kw][c] = W[(size_t)(k0+kw)*N + n0 + c];
            }
        }
        __syncthreads();
        #pragma unroll 8
        for (int kk = 0; kk < 32; ++kk) {
            float4 a0 = *(const float4*)&As[kk][ty*8];
            float4 a1 = *(const float4*)&As[kk][ty*8+4];
            float4 b0 = *(const float4*)&Bs[kk][tx*8];
            float4 b1 = *(const float4*)&Bs[kk][tx*8+4];
            float av[8] = {a0.x,a0.y,a0.z,a0.w,a1.x,a1.y,a1.z,a1.w};
            float bv[8] = {b0.x,b0.y,b0.z,b0.w,b1.x,b1.y,b1.z,b1.w};
            #pragma unroll
            for (int i = 0; i < 8; ++i)
                #pragma unroll
                for (int j = 0; j < 8; ++j)
                    acc[i][j] += av[i]*bv[j];
        }
        __syncthreads();
    }
    #pragma unroll
    for (int i = 0; i < 8; ++i) {
        int row = m0 + ty*8 + i;
        if (row >= M) continue;
        size_t rb = (size_t)row * N;
        #pragma unroll
        for (int j = 0; j < 8; ++j) {
            int col = n0 + tx*8 + j;
            float v = acc[i][j];
            if (bias) v += bias[col];
            if (RESID) v += resid[rb + col];
            stf(&outp[rb + col], v);
        }
    }
}

// ---------------- GEGLU: out[m, 0..2048) = y * gelu_tanh(gate) ----------------
__global__ __launch_bounds__(256)
void geglu_kernel(const bf16* __restrict__ A, const float* __restrict__ W,
                  const float* __restrict__ bias, bf16* __restrict__ outp)
{
    const int K = DIM, NW = 8*DIM, NO = 4*DIM;
    __shared__ __align__(16) float As[32][132];
    __shared__ __align__(16) float Bys[32][132];
    __shared__ __align__(16) float Bgs[32][132];
    const int tid = threadIdx.x;
    const int tx = tid & 15, ty = tid >> 4;
    const int n0 = blockIdx.x * 128, m0 = blockIdx.y * 128;
    float accy[8][8] = {}, accg[8][8] = {};
    for (int k0 = 0; k0 < K; k0 += 32) {
        {
            int kk = tid & 31, r0 = tid >> 5;
            #pragma unroll
            for (int p = 0; p < 16; ++p) {
                int r = r0 + p*8;
                As[kk][r] = b2f(A[(size_t)(m0+r)*K + k0 + kk]);
            }
            int c = tid & 127, kw0 = tid >> 7;
            #pragma unroll
            for (int p = 0; p < 16; ++p) {
                int kw = kw0 + p*2;
                Bys[kw][c] = W[(size_t)(k0+kw)*NW + n0 + c];
                Bgs[kw][c] = W[(size_t)(k0+kw)*NW + NO + n0 + c];
            }
        }
        __syncthreads();
        #pragma unroll 4
        for (int kk = 0; kk < 32; ++kk) {
            float4 a0 = *(const float4*)&As[kk][ty*8];
            float4 a1 = *(const float4*)&As[kk][ty*8+4];
            float4 y0 = *(const float4*)&Bys[kk][tx*8];
            float4 y1 = *(const float4*)&Bys[kk][tx*8+4];
            float4 g0 = *(const float4*)&Bgs[kk][tx*8];
            float4 g1 = *(const float4*)&Bgs[kk][tx*8+4];
            float av[8] = {a0.x,a0.y,a0.z,a0.w,a1.x,a1.y,a1.z,a1.w};
            float yv[8] = {y0.x,y0.y,y0.z,y0.w,y1.x,y1.y,y1.z,y1.w};
            float gv[8] = {g0.x,g0.y,g0.z,g0.w,g1.x,g1.y,g1.z,g1.w};
            #pragma unroll
            for (int i = 0; i < 8; ++i)
                #pragma unroll
                for (int j = 0; j < 8; ++j) {
                    accy[i][j] += av[i]*yv[j];
                    accg[i][j] += av[i]*gv[j];
                }
        }
        __syncthreads();
    }
    #pragma unroll
    for (int i = 0; i < 8; ++i) {
        int row = m0 + ty*8 + i;
        size_t rb = (size_t)row * NO;
        #pragma unroll
        for (int j = 0; j < 8; ++j) {
            int col = n0 + tx*8 + j;
            float y = accy[i][j] + bias[col];
            float g = accg[i][j] + bias[NO + col];
            float t = tanhf(0.7978845608f*g*(1.f + 0.044715f*g*g));
            outp[rb + col] = f2b(y * 0.5f * g * (1.f + t));
        }
    }
}

// ---------------- Flash attention (fp32 vector ALU, bf16 tensors) ----------------
// Block: 64 queries for one (b,h); loop over 64-key tiles; online softmax.
// LDS: qs + one shared K/V tile (reused) + ps  => ~53 KB (stays under 64 KB).
__global__ __launch_bounds__(256)
void attn_kernel(const bf16* __restrict__ Qm, const bf16* __restrict__ Km,
                 const bf16* __restrict__ Vm, bf16* __restrict__ Om, int T)
{
    __shared__ __align__(16) float qs[64][68];
    __shared__ __align__(16) float kv[64][68];
    __shared__ __align__(16) float ps[64][68];
    __shared__ float ms[64], ls[64], as_[64];

    const int tid = threadIdx.x;
    const int b = blockIdx.z, h = blockIdx.y;
    const int q0 = blockIdx.x * 64;

    for (int i = tid; i < 64*64; i += 256) {
        int qi = i >> 6, d = i & 63;
        qs[qi][d] = 0.125f * b2f(Qm[((size_t)(b*SEQ + q0 + qi))*DIM + h*HD + d]);
    }
    if (tid < 64) { ms[tid] = -1e30f; ls[tid] = 0.f; }

    const int qg  = tid >> 4;  // score: 4 queries qg*4..+3
    const int kg  = tid & 15;  // score: 4 keys kg*4..+3
    const int qg2 = tid >> 3;  // PV: 2 queries qg2*2..+1
    const int dg  = tid & 7;   // PV: 8 dims dg*8..+7
    float4 o00 = {0,0,0,0}, o01 = {0,0,0,0}, o10 = {0,0,0,0}, o11 = {0,0,0,0};

    __syncthreads();

    const int ntiles = (T + 63) >> 6;
    for (int t0 = 0; t0 < ntiles; ++t0) {
        const int kb = t0 << 6;
        // ---- stage K tile ----
        for (int i = tid; i < 64*64; i += 256) {
            int ki = i >> 6, d = i & 63;
            int gk = kb + ki;
            kv[ki][d] = (gk < T) ? b2f(Km[((size_t)(b*T + gk))*DIM + h*HD + d]) : 0.f;
        }
        __syncthreads();

        // ---- scores + online softmax ----
        float s[4][4] = {};
        #pragma unroll
        for (int d4 = 0; d4 < 16; ++d4) {
            float4 q4[4], k4[4];
            #pragma unroll
            for (int i = 0; i < 4; ++i) q4[i] = *(const float4*)&qs[qg*4+i][d4*4];
            #pragma unroll
            for (int j = 0; j < 4; ++j) k4[j] = *(const float4*)&kv[kg*4+j][d4*4];
            #pragma unroll
            for (int i = 0; i < 4; ++i)
                #pragma unroll
                for (int j = 0; j < 4; ++j)
                    s[i][j] += q4[i].x*k4[j].x + q4[i].y*k4[j].y
                             + q4[i].z*k4[j].z + q4[i].w*k4[j].w;
        }
        if (kb + 64 > T) {
            #pragma unroll
            for (int j = 0; j < 4; ++j)
                if (kb + kg*4 + j >= T) {
                    s[0][j] = -1e30f; s[1][j] = -1e30f;
                    s[2][j] = -1e30f; s[3][j] = -1e30f;
                }
        }
        #pragma unroll
        for (int i = 0; i < 4; ++i) {
            float mx = fmaxf(fmaxf(s[i][0], s[i][1]), fmaxf(s[i][2], s[i][3]));
            #pragma unroll
            for (int off = 1; off < 16; off <<= 1) mx = fmaxf(mx, __shfl_xor(mx, off));
            int q = qg*4 + i;
            float mold = ms[q];
            float mnew = fmaxf(mold, mx);
            float p[4], psum = 0.f;
            #pragma unroll
            for (int j = 0; j < 4; ++j) { p[j] = __expf(s[i][j] - mnew); psum += p[j]; }
            #pragma unroll
            for (int off = 1; off < 16; off <<= 1) psum += __shfl_xor(psum, off);
            if (kg == 0) {
                float alpha = __expf(mold - mnew);
                ms[q] = mnew;
                ls[q] = ls[q]*alpha + psum;
                as_[q] = alpha;
            }
            *(float4*)&ps[q][kg*4] = make_float4(p[0], p[1], p[2], p[3]);
        }
        __syncthreads();

        // ---- stage V tile over the K tile ----
        for (int i = tid; i < 64*64; i += 256) {
            int ki = i >> 6, d = i & 63;
            int gk = kb + ki;
            kv[ki][d] = (gk < T) ? b2f(Vm[((size_t)(b*T + gk))*DIM + h*HD + d]) : 0.f;
        }
        __syncthreads();

        // ---- PV accumulate ----
        {
            const int qa = qg2*2, qb = qa + 1;
            float a0 = as_[qa], a1 = as_[qb];
            o00.x*=a0; o00.y*=a0; o00.z*=a0; o00.w*=a0;
            o01.x*=a0; o01.y*=a0; o01.z*=a0; o01.w*=a0;
            o10.x*=a1; o10.y*=a1; o10.z*=a1; o10.w*=a1;
            o11.x*=a1; o11.y*=a1; o11.z*=a1; o11.w*=a1;
            #pragma unroll 8
            for (int ki = 0; ki < 64; ++ki) {
                float p0 = ps[qa][ki], p1 = ps[qb][ki];
                float4 va = *(const float4*)&kv[ki][dg*8];
                float4 vb = *(const float4*)&kv[ki][dg*8+4];
                o00.x += p0*va.x; o00.y += p0*va.y; o00.z += p0*va.z; o00.w += p0*va.w;
                o01.x += p0*vb.x; o01.y += p0*vb.y; o01.z += p0*vb.z; o01.w += p0*vb.w;
                o10.x += p1*va.x; o10.y += p1*va.y; o10.z += p1*va.z; o10.w += p1*va.w;
                o11.x += p1*vb.x; o11.y += p1*vb.y; o11.z += p1*vb.z; o11.w += p1*vb.w;
            }
        }
        __syncthreads();
    }

    const int qa = qg2*2, qb = qa + 1;
    float i0 = 1.f/ls[qa], i1 = 1.f/ls[qb];
    size_t base0 = ((size_t)(b*SEQ + q0 + qa))*DIM + h*HD + dg*8;
    size_t base1 = base0 + DIM;
    Om[base0+0]=f2b(o00.x*i0); Om[base0+1]=f2b(o00.y*i0); Om[base0+2]=f2b(o00.z*i0); Om[base0+3]=f2b(o00.w*i0);
    Om[base0+4]=f2b(o01.x*i0); Om[base0+5]=f2b(o01.y*i0); Om[base0+6]=f2b(o01.z*i0); Om[base0+7]=f2b(o01.w*i0);
    Om[base1+0]=f2b(o10.x*i1); Om[base1+1]=f2b(o10.y*i1); Om[base1+2]=f2b(o10.z*i1); Om[base1+3]=f2b(o10.w*i1);
    Om[base1+4]=f2b(o11.x*i1); Om[base1+5]=f2b(o11.y*i1); Om[base1+6]=f2b(o11.z*i1); Om[base1+7]=f2b(o11.w*i1);
}

extern "C" void kernel_launch(void* const* d_in, const int* in_sizes, int n_in,
                              void* d_out, int out_size, void* d_ws, size_t ws_size,
                              hipStream_t stream)
{
    (void)in_sizes; (void)n_in; (void)out_size; (void)ws_size;
    const float* x    = (const float*)d_in[0];
    const float* ctx  = (const float*)d_in[1];
    const float* ln1g = (const float*)d_in[2];
    const float* ln1b = (const float*)d_in[3];
    const float* wq1  = (const float*)d_in[4];
    const float* wk1  = (const float*)d_in[5];
    const float* wv1  = (const float*)d_in[6];
    const float* wo1  = (const float*)d_in[7];
    const float* bo1  = (const float*)d_in[8];
    const float* ln2g = (const float*)d_in[9];
    const float* ln2b = (const float*)d_in[10];
    const float* wq2  = (const float*)d_in[11];
    const float* wk2  = (const float*)d_in[12];
    const float* wv2  = (const float*)d_in[13];
    const float* wo2  = (const float*)d_in[14];
    const float* bo2  = (const float*)d_in[15];
    const float* ln3g = (const float*)d_in[16];
    const float* ln3b = (const float*)d_in[17];
    const float* gw   = (const float*)d_in[18];
    const float* gb   = (const float*)d_in[19];
    const float* ow   = (const float*)d_in[20];
    const float* ob   = (const float*)d_in[21];
    float* out = (float*)d_out;

    // Workspace (bf16 intermediates): An 8MB | Qb 8 | Kb 8 | Vb 8 | Ob 8  = 40MB.
    // FF (8192x2048 bf16 = 32MB) aliases Qb..Ob (dead by GEGLU time).
    // Residual stream H (fp32, 16MB) lives in d_out itself.
    char* ws = (char*)d_ws;
    bf16* An = (bf16*)(ws);
    bf16* Qb = (bf16*)(ws + ((size_t)8<<20));
    bf16* Kb = (bf16*)(ws + ((size_t)16<<20));
    bf16* Vb = (bf16*)(ws + ((size_t)24<<20));
    bf16* Ob = (bf16*)(ws + ((size_t)32<<20));
    bf16* FF = Qb;
    float* Hf = out;

    dim3 blk(256);
    dim3 gLN(NTOK/4);
    dim3 gGEMM(4, 64);        // N=512, M=8192
    dim3 gGEMMs(4, 2);        // N=512, M=154
    dim3 gGEGLU(16, 64);      // N=2048, M=8192
    dim3 gATT(64, NHEAD, BATCH);

    // ---- self-attention ----
    ln_kernel<<<gLN, blk, 0, stream>>>(x, ln1g, ln1b, An, NTOK);
    gemm_kernel<bf16,0,bf16><<<gGEMM, blk, 0, stream>>>(An, wq1, nullptr, nullptr, Qb, NTOK, DIM, DIM);
    gemm_kernel<bf16,0,bf16><<<gGEMM, blk, 0, stream>>>(An, wk1, nullptr, nullptr, Kb, NTOK, DIM, DIM);
    gemm_kernel<bf16,0,bf16><<<gGEMM, blk, 0, stream>>>(An, wv1, nullptr, nullptr, Vb, NTOK, DIM, DIM);
    attn_kernel<<<gATT, blk, 0, stream>>>(Qb, Kb, Vb, Ob, SEQ);
    gemm_kernel<bf16,1,float><<<gGEMM, blk, 0, stream>>>(Ob, wo1, bo1, x, Hf, NTOK, DIM, DIM);

    // ---- cross-attention ----
    ln_kernel<<<gLN, blk, 0, stream>>>(Hf, ln2g, ln2b, An, NTOK);
    gemm_kernel<bf16,0,bf16><<<gGEMM, blk, 0, stream>>>(An, wq2, nullptr, nullptr, Qb, NTOK, DIM, DIM);
    gemm_kernel<float,0,bf16><<<gGEMMs, blk, 0, stream>>>(ctx, wk2, nullptr, nullptr, Kb, NCTX, DIM, DIM);
    gemm_kernel<float,0,bf16><<<gGEMMs, blk, 0, stream>>>(ctx, wv2, nullptr, nullptr, Vb, NCTX, DIM, DIM);
    attn_kernel<<<gATT, blk, 0, stream>>>(Qb, Kb, Vb, Ob, CTXLEN);
    gemm_kernel<bf16,1,float><<<gGEMM, blk, 0, stream>>>(Ob, wo2, bo2, Hf, Hf, NTOK, DIM, DIM);

    // ---- GEGLU FFN + output projection ----
    ln_kernel<<<gLN, blk, 0, stream>>>(Hf, ln3g, ln3b, An, NTOK);
    geglu_kernel<<<gGEGLU, blk, 0, stream>>>(An, gw, gb, FF);
    gemm_kernel<bf16,1,float><<<gGEMM, blk, 0, stream>>>(FF, ow, ob, Hf, out, NTOK, DIM, 4*DIM);
}

// Round 3
// 3037.142 us; speedup vs baseline: 2.3380x; 2.3380x over previous
//
#include <hip/hip_runtime.h>
#include <hip/hip_bf16.h>
#include <math.h>

#define DIM 512
#define NHEAD 8
#define HD 64
#define BATCH 2
#define SEQ 4096
#define CTXLEN 77
#define NTOK (BATCH*SEQ)     // 8192
#define NCTX (BATCH*CTXLEN)  // 154

typedef __hip_bfloat16 bf16;
typedef __attribute__((ext_vector_type(8))) short bf8_t;   // 8 bf16 (4 VGPRs)
typedef __attribute__((ext_vector_type(4))) float f4_t;    // 4 fp32 acc

__device__ __forceinline__ float b2f(bf16 v){ return __bfloat162float(v); }
__device__ __forceinline__ bf16  f2b(float v){ return __float2bfloat16(v); }
__device__ __forceinline__ unsigned short f2bu(float v){ bf16 h = f2b(v); return *(unsigned short*)&h; }
__device__ __forceinline__ float toF(float v){ return v; }
__device__ __forceinline__ float toF(bf16 v){ return __bfloat162float(v); }
__device__ __forceinline__ void  stf(float* p, float v){ *p = v; }
__device__ __forceinline__ void  stf(bf16* p, float v){ *p = f2b(v); }

// ---------------- LayerNorm: one wave per row of 512; fp32 in, bf16 out ----------------
__global__ __launch_bounds__(256)
void ln_kernel(const float* __restrict__ x, const float* __restrict__ g,
               const float* __restrict__ b, bf16* __restrict__ out, int nrows)
{
    int row  = blockIdx.x * 4 + (threadIdx.x >> 6);
    int lane = threadIdx.x & 63;
    if (row >= nrows) return;
    const float* xr = x + (size_t)row * DIM;
    float v[8];
    float s = 0.f, sq = 0.f;
    #pragma unroll
    for (int j = 0; j < 8; ++j) {
        float f = xr[lane + 64*j];
        v[j] = f; s += f; sq += f*f;
    }
    #pragma unroll
    for (int off = 32; off; off >>= 1) {
        s  += __shfl_xor(s,  off);
        sq += __shfl_xor(sq, off);
    }
    float mean = s * (1.f/DIM);
    float var  = sq * (1.f/DIM) - mean*mean;
    float rstd = rsqrtf(var + 1e-5f);
    bf16* orow = out + (size_t)row * DIM;
    #pragma unroll
    for (int j = 0; j < 8; ++j) {
        int c = lane + 64*j;
        orow[c] = f2b((v[j]-mean)*rstd*g[c] + b[c]);
    }
}

// ---------------- GEMM: C = A[MxK] @ W[KxN] (+bias)(+resid fp32) ----------------
// 128x128 tile, BK=32, 8x8 micro-tile, 256 threads. (fp32 VALU — MFMA port next round)
template<typename AT, int RESID, typename OUTT>
__global__ __launch_bounds__(256)
void gemm_kernel(const AT* __restrict__ A, const float* __restrict__ W,
                 const float* __restrict__ bias, const float* __restrict__ resid,
                 OUTT* __restrict__ outp, int M, int N, int K)
{
    __shared__ __align__(16) float As[32][132];  // transposed: [k][m]
    __shared__ __align__(16) float Bs[32][132];  // [k][n]
    const int tid = threadIdx.x;
    const int tx = tid & 15, ty = tid >> 4;
    const int n0 = blockIdx.x * 128, m0 = blockIdx.y * 128;
    float acc[8][8] = {};
    for (int k0 = 0; k0 < K; k0 += 32) {
        {
            int kk = tid & 31, r0 = tid >> 5;
            #pragma unroll
            for (int p = 0; p < 16; ++p) {
                int r = r0 + p*8;
                int row = m0 + r;
                As[kk][r] = (row < M) ? toF(A[(size_t)row*K + k0 + kk]) : 0.f;
            }
            int c = tid & 127, kw0 = tid >> 7;
            #pragma unroll
            for (int p = 0; p < 16; ++p) {
                int kw = kw0 + p*2;
                Bs[kw][c] = W[(size_t)(k0+kw)*N + n0 + c];
            }
        }
        __syncthreads();
        #pragma unroll 8
        for (int kk = 0; kk < 32; ++kk) {
            float4 a0 = *(const float4*)&As[kk][ty*8];
            float4 a1 = *(const float4*)&As[kk][ty*8+4];
            float4 b0 = *(const float4*)&Bs[kk][tx*8];
            float4 b1 = *(const float4*)&Bs[kk][tx*8+4];
            float av[8] = {a0.x,a0.y,a0.z,a0.w,a1.x,a1.y,a1.z,a1.w};
            float bv[8] = {b0.x,b0.y,b0.z,b0.w,b1.x,b1.y,b1.z,b1.w};
            #pragma unroll
            for (int i = 0; i < 8; ++i)
                #pragma unroll
                for (int j = 0; j < 8; ++j)
                    acc[i][j] += av[i]*bv[j];
        }
        __syncthreads();
    }
    #pragma unroll
    for (int i = 0; i < 8; ++i) {
        int row = m0 + ty*8 + i;
        if (row >= M) continue;
        size_t rb = (size_t)row * N;
        #pragma unroll
        for (int j = 0; j < 8; ++j) {
            int col = n0 + tx*8 + j;
            float v = acc[i][j];
            if (bias) v += bias[col];
            if (RESID) v += resid[rb + col];
            stf(&outp[rb + col], v);
        }
    }
}

// ---------------- GEGLU: out[m, 0..2048) = y * gelu_tanh(gate) ----------------
__global__ __launch_bounds__(256)
void geglu_kernel(const bf16* __restrict__ A, const float* __restrict__ W,
                  const float* __restrict__ bias, bf16* __restrict__ outp)
{
    const int K = DIM, NW = 8*DIM, NO = 4*DIM;
    __shared__ __align__(16) float As[32][132];
    __shared__ __align__(16) float Bys[32][132];
    __shared__ __align__(16) float Bgs[32][132];
    const int tid = threadIdx.x;
    const int tx = tid & 15, ty = tid >> 4;
    const int n0 = blockIdx.x * 128, m0 = blockIdx.y * 128;
    float accy[8][8] = {}, accg[8][8] = {};
    for (int k0 = 0; k0 < K; k0 += 32) {
        {
            int kk = tid & 31, r0 = tid >> 5;
            #pragma unroll
            for (int p = 0; p < 16; ++p) {
                int r = r0 + p*8;
                As[kk][r] = b2f(A[(size_t)(m0+r)*K + k0 + kk]);
            }
            int c = tid & 127, kw0 = tid >> 7;
            #pragma unroll
            for (int p = 0; p < 16; ++p) {
                int kw = kw0 + p*2;
                Bys[kw][c] = W[(size_t)(k0+kw)*NW + n0 + c];
                Bgs[kw][c] = W[(size_t)(k0+kw)*NW + NO + n0 + c];
            }
        }
        __syncthreads();
        #pragma unroll 4
        for (int kk = 0; kk < 32; ++kk) {
            float4 a0 = *(const float4*)&As[kk][ty*8];
            float4 a1 = *(const float4*)&As[kk][ty*8+4];
            float4 y0 = *(const float4*)&Bys[kk][tx*8];
            float4 y1 = *(const float4*)&Bys[kk][tx*8+4];
            float4 g0 = *(const float4*)&Bgs[kk][tx*8];
            float4 g1 = *(const float4*)&Bgs[kk][tx*8+4];
            float av[8] = {a0.x,a0.y,a0.z,a0.w,a1.x,a1.y,a1.z,a1.w};
            float yv[8] = {y0.x,y0.y,y0.z,y0.w,y1.x,y1.y,y1.z,y1.w};
            float gv[8] = {g0.x,g0.y,g0.z,g0.w,g1.x,g1.y,g1.z,g1.w};
            #pragma unroll
            for (int i = 0; i < 8; ++i)
                #pragma unroll
                for (int j = 0; j < 8; ++j) {
                    accy[i][j] += av[i]*yv[j];
                    accg[i][j] += av[i]*gv[j];
                }
        }
        __syncthreads();
    }
    #pragma unroll
    for (int i = 0; i < 8; ++i) {
        int row = m0 + ty*8 + i;
        size_t rb = (size_t)row * NO;
        #pragma unroll
        for (int j = 0; j < 8; ++j) {
            int col = n0 + tx*8 + j;
            float y = accy[i][j] + bias[col];
            float g = accg[i][j] + bias[NO + col];
            float t = tanhf(0.7978845608f*g*(1.f + 0.044715f*g*g));
            outp[rb + col] = f2b(y * 0.5f * g * (1.f + t));
        }
    }
}

// ---------------- MFMA flash attention ----------------
// Block = 256 threads (4 waves), 128 queries, one (b,h). Wave w owns queries
// [w*32, w*32+32) as two 16-row m-tiles. Per 64-key tile: stage K[key][dim] and
// V^T[dim][key] in LDS (rows padded to 72 bf16 = 144 B, 16B-aligned, bank+4),
// QK^T via mfma_f32_16x16x32_bf16 (A=Q frag, B=K rows), online softmax in
// registers on C-layout (row=quad*4+r, col=lane&15; row-reduce = 16-lane
// shfl_xor), P -> per-wave LDS (bf16) -> A-frag, PV via MFMA into f32 accs.
__global__ __launch_bounds__(256)
void attn_mfma_kernel(const bf16* __restrict__ Qm, const bf16* __restrict__ Km,
                      const bf16* __restrict__ Vm, bf16* __restrict__ Om, int T)
{
    __shared__ __align__(16) unsigned short Ks[64][72];
    __shared__ __align__(16) unsigned short Vt[64][72];
    __shared__ __align__(16) unsigned short Ps[8][16][72];

    const int tid  = threadIdx.x;
    const int wave = tid >> 6;
    const int lane = tid & 63;
    const int l16  = lane & 15;
    const int quad = lane >> 4;
    const int b = blockIdx.z, h = blockIdx.y;
    const int qblk = blockIdx.x * 128;

    // Q A-fragments: A[m=lane&15][k=quad*8+j], two k-chunks of 32, two m-tiles
    bf8_t qf[2][2];
    #pragma unroll
    for (int mt = 0; mt < 2; ++mt) {
        const bf16* qp = Qm + ((size_t)(b*SEQ + qblk + wave*32 + mt*16 + l16))*DIM + h*HD + quad*8;
        qf[mt][0] = *(const bf8_t*)qp;
        qf[mt][1] = *(const bf8_t*)(qp + 32);
    }

    f4_t o[2][4];
    float m_run[2][4], l_run[2][4];
    #pragma unroll
    for (int mt = 0; mt < 2; ++mt) {
        #pragma unroll
        for (int nt = 0; nt < 4; ++nt) o[mt][nt] = f4_t{0.f,0.f,0.f,0.f};
        #pragma unroll
        for (int r = 0; r < 4; ++r) { m_run[mt][r] = -1e30f; l_run[mt][r] = 0.f; }
    }

    const int ntiles = (T + 63) >> 6;
    for (int t0 = 0; t0 < ntiles; ++t0) {
        const int kb = t0 << 6;
        if (t0) __syncthreads();   // previous tile's reads done before restage
        // ---- stage K tile and V^T tile (4096 elems each, 8-wide vectors) ----
        #pragma unroll
        for (int it = 0; it < 2; ++it) {
            int e = tid + it*256;
            int key = e >> 3, dg = (e & 7)*8;
            int gk = kb + key;
            bf8_t kv = {0,0,0,0,0,0,0,0};
            bf8_t vv = {0,0,0,0,0,0,0,0};
            if (gk < T) {
                size_t off = ((size_t)(b*T + gk))*DIM + h*HD + dg;
                kv = *(const bf8_t*)(Km + off);
                vv = *(const bf8_t*)(Vm + off);
            }
            *(bf8_t*)&Ks[key][dg] = kv;
            #pragma unroll
            for (int j = 0; j < 8; ++j) Vt[dg + j][key] = ((unsigned short*)&vv)[j];
        }
        __syncthreads();

        #pragma unroll
        for (int mt = 0; mt < 2; ++mt) {
            // ---- QK^T: scores[row=quad*4+r][key=nt*16+l16] ----
            f4_t sc[4];
            #pragma unroll
            for (int nt = 0; nt < 4; ++nt) {
                f4_t c = {0.f,0.f,0.f,0.f};
                bf8_t k0 = *(const bf8_t*)&Ks[nt*16 + l16][quad*8];
                bf8_t k1 = *(const bf8_t*)&Ks[nt*16 + l16][32 + quad*8];
                c = __builtin_amdgcn_mfma_f32_16x16x32_bf16(qf[mt][0], k0, c, 0, 0, 0);
                c = __builtin_amdgcn_mfma_f32_16x16x32_bf16(qf[mt][1], k1, c, 0, 0, 0);
                sc[nt] = c;
            }
            #pragma unroll
            for (int nt = 0; nt < 4; ++nt) {
                #pragma unroll
                for (int r = 0; r < 4; ++r) sc[nt][r] *= 0.125f;
            }
            if (kb + 64 > T) {
                #pragma unroll
                for (int nt = 0; nt < 4; ++nt)
                    if (kb + nt*16 + l16 >= T) {
                        sc[nt][0] = -1e30f; sc[nt][1] = -1e30f;
                        sc[nt][2] = -1e30f; sc[nt][3] = -1e30f;
                    }
            }
            // ---- online softmax (rows shared by 16 lanes of each quad) ----
            float alpha[4];
            #pragma unroll
            for (int r = 0; r < 4; ++r) {
                float mx = fmaxf(fmaxf(sc[0][r], sc[1][r]), fmaxf(sc[2][r], sc[3][r]));
                #pragma unroll
                for (int off = 1; off < 16; off <<= 1) mx = fmaxf(mx, __shfl_xor(mx, off));
                float mold = m_run[mt][r];
                float mnew = fmaxf(mold, mx);
                float psum = 0.f;
                #pragma unroll
                for (int nt = 0; nt < 4; ++nt) {
                    float p = __expf(sc[nt][r] - mnew);
                    sc[nt][r] = p; psum += p;
                }
                #pragma unroll
                for (int off = 1; off < 16; off <<= 1) psum += __shfl_xor(psum, off);
                alpha[r] = __expf(mold - mnew);
                m_run[mt][r] = mnew;
                l_run[mt][r] = l_run[mt][r]*alpha[r] + psum;
            }
            // ---- P (C-layout) -> per-wave LDS (A-layout source) ----
            #pragma unroll
            for (int nt = 0; nt < 4; ++nt)
                #pragma unroll
                for (int r = 0; r < 4; ++r)
                    Ps[wave*2+mt][quad*4+r][nt*16 + l16] = f2bu(sc[nt][r]);
            // ---- rescale O by alpha ----
            #pragma unroll
            for (int nt = 0; nt < 4; ++nt)
                #pragma unroll
                for (int r = 0; r < 4; ++r)
                    o[mt][nt][r] *= alpha[r];
            // ---- PV: A = P frag, B = V^T rows ----
            #pragma unroll
            for (int kc = 0; kc < 2; ++kc) {
                bf8_t pa = *(const bf8_t*)&Ps[wave*2+mt][l16][kc*32 + quad*8];
                #pragma unroll
                for (int nt = 0; nt < 4; ++nt) {
                    bf8_t vb = *(const bf8_t*)&Vt[nt*16 + l16][kc*32 + quad*8];
                    o[mt][nt] = __builtin_amdgcn_mfma_f32_16x16x32_bf16(pa, vb, o[mt][nt], 0, 0, 0);
                }
            }
        }
    }

    // ---- epilogue: O /= l, write bf16 ----
    #pragma unroll
    for (int mt = 0; mt < 2; ++mt) {
        #pragma unroll
        for (int r = 0; r < 4; ++r) {
            float inv = 1.f / l_run[mt][r];
            int tok = qblk + wave*32 + mt*16 + quad*4 + r;
            size_t base = ((size_t)(b*SEQ + tok))*DIM + h*HD;
            #pragma unroll
            for (int nt = 0; nt < 4; ++nt)
                Om[base + nt*16 + l16] = f2b(o[mt][nt][r] * inv);
        }
    }
}

extern "C" void kernel_launch(void* const* d_in, const int* in_sizes, int n_in,
                              void* d_out, int out_size, void* d_ws, size_t ws_size,
                              hipStream_t stream)
{
    (void)in_sizes; (void)n_in; (void)out_size; (void)ws_size;
    const float* x    = (const float*)d_in[0];
    const float* ctx  = (const float*)d_in[1];
    const float* ln1g = (const float*)d_in[2];
    const float* ln1b = (const float*)d_in[3];
    const float* wq1  = (const float*)d_in[4];
    const float* wk1  = (const float*)d_in[5];
    const float* wv1  = (const float*)d_in[6];
    const float* wo1  = (const float*)d_in[7];
    const float* bo1  = (const float*)d_in[8];
    const float* ln2g = (const float*)d_in[9];
    const float* ln2b = (const float*)d_in[10];
    const float* wq2  = (const float*)d_in[11];
    const float* wk2  = (const float*)d_in[12];
    const float* wv2  = (const float*)d_in[13];
    const float* wo2  = (const float*)d_in[14];
    const float* bo2  = (const float*)d_in[15];
    const float* ln3g = (const float*)d_in[16];
    const float* ln3b = (const float*)d_in[17];
    const float* gw   = (const float*)d_in[18];
    const float* gb   = (const float*)d_in[19];
    const float* ow   = (const float*)d_in[20];
    const float* ob   = (const float*)d_in[21];
    float* out = (float*)d_out;

    // Workspace (bf16 intermediates): An 8MB | Qb 8 | Kb 8 | Vb 8 | Ob 8 = 40MB.
    // FF (8192x2048 bf16 = 32MB) aliases Qb..Ob (dead by GEGLU time).
    // Residual stream H (fp32, 16MB) lives in d_out itself.
    char* ws = (char*)d_ws;
    bf16* An = (bf16*)(ws);
    bf16* Qb = (bf16*)(ws + ((size_t)8<<20));
    bf16* Kb = (bf16*)(ws + ((size_t)16<<20));
    bf16* Vb = (bf16*)(ws + ((size_t)24<<20));
    bf16* Ob = (bf16*)(ws + ((size_t)32<<20));
    bf16* FF = Qb;
    float* Hf = out;

    dim3 blk(256);
    dim3 gLN(NTOK/4);
    dim3 gGEMM(4, 64);        // N=512, M=8192
    dim3 gGEMMs(4, 2);        // N=512, M=154
    dim3 gGEGLU(16, 64);      // N=2048, M=8192
    dim3 gATT(SEQ/128, NHEAD, BATCH);

    // ---- self-attention ----
    ln_kernel<<<gLN, blk, 0, stream>>>(x, ln1g, ln1b, An, NTOK);
    gemm_kernel<bf16,0,bf16><<<gGEMM, blk, 0, stream>>>(An, wq1, nullptr, nullptr, Qb, NTOK, DIM, DIM);
    gemm_kernel<bf16,0,bf16><<<gGEMM, blk, 0, stream>>>(An, wk1, nullptr, nullptr, Kb, NTOK, DIM, DIM);
    gemm_kernel<bf16,0,bf16><<<gGEMM, blk, 0, stream>>>(An, wv1, nullptr, nullptr, Vb, NTOK, DIM, DIM);
    attn_mfma_kernel<<<gATT, blk, 0, stream>>>(Qb, Kb, Vb, Ob, SEQ);
    gemm_kernel<bf16,1,float><<<gGEMM, blk, 0, stream>>>(Ob, wo1, bo1, x, Hf, NTOK, DIM, DIM);

    // ---- cross-attention ----
    ln_kernel<<<gLN, blk, 0, stream>>>(Hf, ln2g, ln2b, An, NTOK);
    gemm_kernel<bf16,0,bf16><<<gGEMM, blk, 0, stream>>>(An, wq2, nullptr, nullptr, Qb, NTOK, DIM, DIM);
    gemm_kernel<float,0,bf16><<<gGEMMs, blk, 0, stream>>>(ctx, wk2, nullptr, nullptr, Kb, NCTX, DIM, DIM);
    gemm_kernel<float,0,bf16><<<gGEMMs, blk, 0, stream>>>(ctx, wv2, nullptr, nullptr, Vb, NCTX, DIM, DIM);
    attn_mfma_kernel<<<gATT, blk, 0, stream>>>(Qb, Kb, Vb, Ob, CTXLEN);
    gemm_kernel<bf16,1,float><<<gGEMM, blk, 0, stream>>>(Ob, wo2, bo2, Hf, Hf, NTOK, DIM, DIM);

    // ---- GEGLU FFN + output projection ----
    ln_kernel<<<gLN, blk, 0, stream>>>(Hf, ln3g, ln3b, An, NTOK);
    geglu_kernel<<<gGEGLU, blk, 0, stream>>>(An, gw, gb, FF);
    gemm_kernel<bf16,1,float><<<gGEMM, blk, 0, stream>>>(FF, ow, ob, Hf, out, NTOK, DIM, 4*DIM);
}

// Round 4
// 739.283 us; speedup vs baseline: 9.6050x; 4.1082x over previous
//
#include <hip/hip_runtime.h>
#include <hip/hip_bf16.h>
#include <math.h>

#define DIM 512
#define NHEAD 8
#define HD 64
#define BATCH 2
#define SEQ 4096
#define CTXLEN 77
#define NTOK (BATCH*SEQ)     // 8192
#define NCTX (BATCH*CTXLEN)  // 154

typedef __hip_bfloat16 bf16;
typedef __attribute__((ext_vector_type(8))) short bf8_t;   // 8 bf16 (4 VGPRs)
typedef __attribute__((ext_vector_type(4))) float f4_t;    // 4 fp32 acc

__device__ __forceinline__ float b2f(bf16 v){ return __bfloat162float(v); }
__device__ __forceinline__ bf16  f2b(float v){ return __float2bfloat16(v); }
__device__ __forceinline__ unsigned short f2bu(float v){ bf16 h = f2b(v); return *(unsigned short*)&h; }
__device__ __forceinline__ void  stf(float* p, float v){ *p = v; }
__device__ __forceinline__ void  stf(bf16* p, float v){ *p = f2b(v); }

// ---------------- LayerNorm: one wave per row of 512; fp32 in, bf16 out ----------------
__global__ __launch_bounds__(256)
void ln_kernel(const float* __restrict__ x, const float* __restrict__ g,
               const float* __restrict__ b, bf16* __restrict__ out, int nrows)
{
    int row  = blockIdx.x * 4 + (threadIdx.x >> 6);
    int lane = threadIdx.x & 63;
    if (row >= nrows) return;
    const float* xr = x + (size_t)row * DIM;
    float v[8];
    float s = 0.f, sq = 0.f;
    #pragma unroll
    for (int j = 0; j < 8; ++j) {
        float f = xr[lane + 64*j];
        v[j] = f; s += f; sq += f*f;
    }
    #pragma unroll
    for (int off = 32; off; off >>= 1) {
        s  += __shfl_xor(s,  off);
        sq += __shfl_xor(sq, off);
    }
    float mean = s * (1.f/DIM);
    float var  = sq * (1.f/DIM) - mean*mean;
    float rstd = rsqrtf(var + 1e-5f);
    bf16* orow = out + (size_t)row * DIM;
    #pragma unroll
    for (int j = 0; j < 8; ++j) {
        int c = lane + 64*j;
        orow[c] = f2b((v[j]-mean)*rstd*g[c] + b[c]);
    }
}

// ---------------- weight prep: fp32 [K][N] -> bf16 [N][K] (transpose+cast) ----------------
__global__ __launch_bounds__(256)
void transpose_bf16_kernel(const float* __restrict__ W, bf16* __restrict__ Wt, int K, int N)
{
    __shared__ float tile[32][33];
    int n0 = blockIdx.x * 32, k0 = blockIdx.y * 32;
    int tx = threadIdx.x & 31, ty = threadIdx.x >> 5; // ty 0..7
    #pragma unroll
    for (int p = 0; p < 4; ++p)
        tile[ty + p*8][tx] = W[(size_t)(k0 + ty + p*8)*N + n0 + tx];
    __syncthreads();
    #pragma unroll
    for (int p = 0; p < 4; ++p)
        Wt[(size_t)(n0 + ty + p*8)*K + k0 + tx] = f2b(tile[tx][ty + p*8]);
}

struct TPtrs { const float* src[8]; bf16* dst[8]; };
// all 8 square 512x512 weights in one launch: grid (16,16,8)
__global__ __launch_bounds__(256)
void transpose8_kernel(TPtrs p)
{
    __shared__ float tile[32][33];
    const float* W = p.src[blockIdx.z];
    bf16* Wt = p.dst[blockIdx.z];
    int n0 = blockIdx.x * 32, k0 = blockIdx.y * 32;
    int tx = threadIdx.x & 31, ty = threadIdx.x >> 5;
    #pragma unroll
    for (int q = 0; q < 4; ++q)
        tile[ty + q*8][tx] = W[(size_t)(k0 + ty + q*8)*512 + n0 + tx];
    __syncthreads();
    #pragma unroll
    for (int q = 0; q < 4; ++q)
        Wt[(size_t)(n0 + ty + q*8)*512 + k0 + tx] = f2b(tile[tx][ty + q*8]);
}

__global__ __launch_bounds__(256)
void cast_bf16_kernel(const float* __restrict__ in, bf16* __restrict__ out, int n)
{
    int i = blockIdx.x*256 + threadIdx.x;
    if (i < n) out[i] = f2b(in[i]);
}

// ---------------- MFMA GEMM: C = A[MxK](bf16) @ Wt[NxK]^T (+bias fp32)(+resid fp32) ----------------
// 128x128 tile, BK=64, 4 waves in 2x2, each wave 64x64 = 4x4 MFMA tiles.
// LDS k-major, XOR-swizzled in 16B chunks -> conflict-free ds_read_b128.
template<int RESID, typename OUTT, bool GUARD>
__global__ __launch_bounds__(256)
void gemm_mfma_kernel(const bf16* __restrict__ A, const bf16* __restrict__ Wt,
                      const float* __restrict__ bias, const float* __restrict__ resid,
                      OUTT* __restrict__ outp, int M, int N, int K)
{
    __shared__ __align__(16) unsigned short As[128*64];
    __shared__ __align__(16) unsigned short Bs[128*64];
    const int tid  = threadIdx.x;
    const int wave = tid >> 6, lane = tid & 63;
    const int l16  = lane & 15, quad = lane >> 4;
    const int wm = (wave >> 1) * 64, wn = (wave & 1) * 64;
    const int m0 = blockIdx.y * 128, n0 = blockIdx.x * 128;
    const int srow = tid >> 3, scol = tid & 7;   // staging: 8 chunks of 16B per 64-elem row

    f4_t acc[4][4];
    #pragma unroll
    for (int i = 0; i < 4; ++i)
        #pragma unroll
        for (int j = 0; j < 4; ++j) acc[i][j] = f4_t{0.f,0.f,0.f,0.f};

    for (int k0 = 0; k0 < K; k0 += 64) {
        #pragma unroll
        for (int p = 0; p < 4; ++p) {
            int r = srow + p*32;
            int gr = m0 + r;
            if (GUARD) gr = (gr < M) ? gr : (M-1);
            bf8_t v = *(const bf8_t*)(A + (size_t)gr*K + k0 + scol*8);
            *(bf8_t*)&As[r*64 + ((scol ^ (r&7))*8)] = v;
        }
        #pragma unroll
        for (int p = 0; p < 4; ++p) {
            int r = srow + p*32;
            bf8_t v = *(const bf8_t*)(Wt + (size_t)(n0 + r)*K + k0 + scol*8);
            *(bf8_t*)&Bs[r*64 + ((scol ^ (r&7))*8)] = v;
        }
        __syncthreads();
        #pragma unroll
        for (int kc = 0; kc < 2; ++kc) {
            const int cg = kc*4 + quad;
            bf8_t af[4], bfr[4];
            #pragma unroll
            for (int mt = 0; mt < 4; ++mt) {
                int r = wm + mt*16 + l16;
                af[mt] = *(const bf8_t*)&As[r*64 + ((cg ^ (r&7))*8)];
            }
            #pragma unroll
            for (int nt = 0; nt < 4; ++nt) {
                int r = wn + nt*16 + l16;
                bfr[nt] = *(const bf8_t*)&Bs[r*64 + ((cg ^ (r&7))*8)];
            }
            #pragma unroll
            for (int mt = 0; mt < 4; ++mt)
                #pragma unroll
                for (int nt = 0; nt < 4; ++nt)
                    acc[mt][nt] = __builtin_amdgcn_mfma_f32_16x16x32_bf16(af[mt], bfr[nt], acc[mt][nt], 0, 0, 0);
        }
        __syncthreads();
    }

    #pragma unroll
    for (int mt = 0; mt < 4; ++mt) {
        #pragma unroll
        for (int r_ = 0; r_ < 4; ++r_) {
            int row = m0 + wm + mt*16 + quad*4 + r_;
            if (GUARD && row >= M) continue;
            size_t rb = (size_t)row * N;
            #pragma unroll
            for (int nt = 0; nt < 4; ++nt) {
                int col = n0 + wn + nt*16 + l16;
                float v = acc[mt][nt][r_];
                if (bias) v += bias[col];
                if (RESID) v += resid[rb + col];
                stf(&outp[rb + col], v);
            }
        }
    }
}

// ---------------- MFMA GEGLU: out[m,n] = y * gelu_tanh(gate), n in [0,2048) ----------------
// WtG bf16 [4096][512]: rows [0,2048) = y weights, [2048,4096) = gate weights.
// Tile 128m x 64n, 4 waves stacked in m (32 rows each), dual accumulators.
__global__ __launch_bounds__(256)
void geglu_mfma_kernel(const bf16* __restrict__ A, const bf16* __restrict__ WtG,
                       const float* __restrict__ bias, bf16* __restrict__ outp)
{
    __shared__ __align__(16) unsigned short As[128*64];
    __shared__ __align__(16) unsigned short Bys[64*64];
    __shared__ __align__(16) unsigned short Bgs[64*64];
    const int tid  = threadIdx.x;
    const int wave = tid >> 6, lane = tid & 63;
    const int l16  = lane & 15, quad = lane >> 4;
    const int m0 = blockIdx.y * 128, n0 = blockIdx.x * 64;
    const int srow = tid >> 3, scol = tid & 7;

    f4_t accy[2][4], accg[2][4];
    #pragma unroll
    for (int i = 0; i < 2; ++i)
        #pragma unroll
        for (int j = 0; j < 4; ++j) { accy[i][j] = f4_t{0.f,0.f,0.f,0.f}; accg[i][j] = f4_t{0.f,0.f,0.f,0.f}; }

    for (int k0 = 0; k0 < DIM; k0 += 64) {
        #pragma unroll
        for (int p = 0; p < 4; ++p) {
            int r = srow + p*32;
            bf8_t v = *(const bf8_t*)(A + (size_t)(m0 + r)*DIM + k0 + scol*8);
            *(bf8_t*)&As[r*64 + ((scol ^ (r&7))*8)] = v;
        }
        #pragma unroll
        for (int p = 0; p < 2; ++p) {
            int r = srow + p*32;
            bf8_t vy = *(const bf8_t*)(WtG + (size_t)(n0 + r)*DIM + k0 + scol*8);
            bf8_t vg = *(const bf8_t*)(WtG + (size_t)(2048 + n0 + r)*DIM + k0 + scol*8);
            *(bf8_t*)&Bys[r*64 + ((scol ^ (r&7))*8)] = vy;
            *(bf8_t*)&Bgs[r*64 + ((scol ^ (r&7))*8)] = vg;
        }
        __syncthreads();
        #pragma unroll
        for (int kc = 0; kc < 2; ++kc) {
            const int cg = kc*4 + quad;
            bf8_t af[2];
            #pragma unroll
            for (int mt = 0; mt < 2; ++mt) {
                int r = wave*32 + mt*16 + l16;
                af[mt] = *(const bf8_t*)&As[r*64 + ((cg ^ (r&7))*8)];
            }
            #pragma unroll
            for (int nt = 0; nt < 4; ++nt) {
                int r = nt*16 + l16;
                bf8_t by = *(const bf8_t*)&Bys[r*64 + ((cg ^ (r&7))*8)];
                bf8_t bg = *(const bf8_t*)&Bgs[r*64 + ((cg ^ (r&7))*8)];
                #pragma unroll
                for (int mt = 0; mt < 2; ++mt) {
                    accy[mt][nt] = __builtin_amdgcn_mfma_f32_16x16x32_bf16(af[mt], by, accy[mt][nt], 0, 0, 0);
                    accg[mt][nt] = __builtin_amdgcn_mfma_f32_16x16x32_bf16(af[mt], bg, accg[mt][nt], 0, 0, 0);
                }
            }
        }
        __syncthreads();
    }

    #pragma unroll
    for (int mt = 0; mt < 2; ++mt) {
        #pragma unroll
        for (int r_ = 0; r_ < 4; ++r_) {
            int row = m0 + wave*32 + mt*16 + quad*4 + r_;
            size_t rb = (size_t)row * 2048;
            #pragma unroll
            for (int nt = 0; nt < 4; ++nt) {
                int col = n0 + nt*16 + l16;
                float y = accy[mt][nt][r_] + bias[col];
                float g = accg[mt][nt][r_] + bias[2048 + col];
                float t = tanhf(0.7978845608f*g*(1.f + 0.044715f*g*g));
                outp[rb + col] = f2b(y * 0.5f * g * (1.f + t));
            }
        }
    }
}

// ---------------- MFMA flash attention (unchanged from R2) ----------------
__global__ __launch_bounds__(256)
void attn_mfma_kernel(const bf16* __restrict__ Qm, const bf16* __restrict__ Km,
                      const bf16* __restrict__ Vm, bf16* __restrict__ Om, int T)
{
    __shared__ __align__(16) unsigned short Ks[64][72];
    __shared__ __align__(16) unsigned short Vt[64][72];
    __shared__ __align__(16) unsigned short Ps[8][16][72];

    const int tid  = threadIdx.x;
    const int wave = tid >> 6;
    const int lane = tid & 63;
    const int l16  = lane & 15;
    const int quad = lane >> 4;
    const int b = blockIdx.z, h = blockIdx.y;
    const int qblk = blockIdx.x * 128;

    bf8_t qf[2][2];
    #pragma unroll
    for (int mt = 0; mt < 2; ++mt) {
        const bf16* qp = Qm + ((size_t)(b*SEQ + qblk + wave*32 + mt*16 + l16))*DIM + h*HD + quad*8;
        qf[mt][0] = *(const bf8_t*)qp;
        qf[mt][1] = *(const bf8_t*)(qp + 32);
    }

    f4_t o[2][4];
    float m_run[2][4], l_run[2][4];
    #pragma unroll
    for (int mt = 0; mt < 2; ++mt) {
        #pragma unroll
        for (int nt = 0; nt < 4; ++nt) o[mt][nt] = f4_t{0.f,0.f,0.f,0.f};
        #pragma unroll
        for (int r = 0; r < 4; ++r) { m_run[mt][r] = -1e30f; l_run[mt][r] = 0.f; }
    }

    const int ntiles = (T + 63) >> 6;
    for (int t0 = 0; t0 < ntiles; ++t0) {
        const int kb = t0 << 6;
        if (t0) __syncthreads();
        #pragma unroll
        for (int it = 0; it < 2; ++it) {
            int e = tid + it*256;
            int key = e >> 3, dg = (e & 7)*8;
            int gk = kb + key;
            bf8_t kv = {0,0,0,0,0,0,0,0};
            bf8_t vv = {0,0,0,0,0,0,0,0};
            if (gk < T) {
                size_t off = ((size_t)(b*T + gk))*DIM + h*HD + dg;
                kv = *(const bf8_t*)(Km + off);
                vv = *(const bf8_t*)(Vm + off);
            }
            *(bf8_t*)&Ks[key][dg] = kv;
            #pragma unroll
            for (int j = 0; j < 8; ++j) Vt[dg + j][key] = ((unsigned short*)&vv)[j];
        }
        __syncthreads();

        #pragma unroll
        for (int mt = 0; mt < 2; ++mt) {
            f4_t sc[4];
            #pragma unroll
            for (int nt = 0; nt < 4; ++nt) {
                f4_t c = {0.f,0.f,0.f,0.f};
                bf8_t k0 = *(const bf8_t*)&Ks[nt*16 + l16][quad*8];
                bf8_t k1 = *(const bf8_t*)&Ks[nt*16 + l16][32 + quad*8];
                c = __builtin_amdgcn_mfma_f32_16x16x32_bf16(qf[mt][0], k0, c, 0, 0, 0);
                c = __builtin_amdgcn_mfma_f32_16x16x32_bf16(qf[mt][1], k1, c, 0, 0, 0);
                sc[nt] = c;
            }
            #pragma unroll
            for (int nt = 0; nt < 4; ++nt) {
                #pragma unroll
                for (int r = 0; r < 4; ++r) sc[nt][r] *= 0.125f;
            }
            if (kb + 64 > T) {
                #pragma unroll
                for (int nt = 0; nt < 4; ++nt)
                    if (kb + nt*16 + l16 >= T) {
                        sc[nt][0] = -1e30f; sc[nt][1] = -1e30f;
                        sc[nt][2] = -1e30f; sc[nt][3] = -1e30f;
                    }
            }
            float alpha[4];
            #pragma unroll
            for (int r = 0; r < 4; ++r) {
                float mx = fmaxf(fmaxf(sc[0][r], sc[1][r]), fmaxf(sc[2][r], sc[3][r]));
                #pragma unroll
                for (int off = 1; off < 16; off <<= 1) mx = fmaxf(mx, __shfl_xor(mx, off));
                float mold = m_run[mt][r];
                float mnew = fmaxf(mold, mx);
                float psum = 0.f;
                #pragma unroll
                for (int nt = 0; nt < 4; ++nt) {
                    float p = __expf(sc[nt][r] - mnew);
                    sc[nt][r] = p; psum += p;
                }
                #pragma unroll
                for (int off = 1; off < 16; off <<= 1) psum += __shfl_xor(psum, off);
                alpha[r] = __expf(mold - mnew);
                m_run[mt][r] = mnew;
                l_run[mt][r] = l_run[mt][r]*alpha[r] + psum;
            }
            #pragma unroll
            for (int nt = 0; nt < 4; ++nt)
                #pragma unroll
                for (int r = 0; r < 4; ++r)
                    Ps[wave*2+mt][quad*4+r][nt*16 + l16] = f2bu(sc[nt][r]);
            #pragma unroll
            for (int nt = 0; nt < 4; ++nt)
                #pragma unroll
                for (int r = 0; r < 4; ++r)
                    o[mt][nt][r] *= alpha[r];
            #pragma unroll
            for (int kc = 0; kc < 2; ++kc) {
                bf8_t pa = *(const bf8_t*)&Ps[wave*2+mt][l16][kc*32 + quad*8];
                #pragma unroll
                for (int nt = 0; nt < 4; ++nt) {
                    bf8_t vb = *(const bf8_t*)&Vt[nt*16 + l16][kc*32 + quad*8];
                    o[mt][nt] = __builtin_amdgcn_mfma_f32_16x16x32_bf16(pa, vb, o[mt][nt], 0, 0, 0);
                }
            }
        }
    }

    #pragma unroll
    for (int mt = 0; mt < 2; ++mt) {
        #pragma unroll
        for (int r = 0; r < 4; ++r) {
            float inv = 1.f / l_run[mt][r];
            int tok = qblk + wave*32 + mt*16 + quad*4 + r;
            size_t base = ((size_t)(b*SEQ + tok))*DIM + h*HD;
            #pragma unroll
            for (int nt = 0; nt < 4; ++nt)
                Om[base + nt*16 + l16] = f2b(o[mt][nt][r] * inv);
        }
    }
}

extern "C" void kernel_launch(void* const* d_in, const int* in_sizes, int n_in,
                              void* d_out, int out_size, void* d_ws, size_t ws_size,
                              hipStream_t stream)
{
    (void)in_sizes; (void)n_in; (void)out_size; (void)ws_size;
    const float* x    = (const float*)d_in[0];
    const float* ctx  = (const float*)d_in[1];
    const float* ln1g = (const float*)d_in[2];
    const float* ln1b = (const float*)d_in[3];
    const float* wq1  = (const float*)d_in[4];
    const float* wk1  = (const float*)d_in[5];
    const float* wv1  = (const float*)d_in[6];
    const float* wo1  = (const float*)d_in[7];
    const float* bo1  = (const float*)d_in[8];
    const float* ln2g = (const float*)d_in[9];
    const float* ln2b = (const float*)d_in[10];
    const float* wq2  = (const float*)d_in[11];
    const float* wk2  = (const float*)d_in[12];
    const float* wv2  = (const float*)d_in[13];
    const float* wo2  = (const float*)d_in[14];
    const float* bo2  = (const float*)d_in[15];
    const float* ln3g = (const float*)d_in[16];
    const float* ln3b = (const float*)d_in[17];
    const float* gw   = (const float*)d_in[18];
    const float* gb   = (const float*)d_in[19];
    const float* ow   = (const float*)d_in[20];
    const float* ob   = (const float*)d_in[21];
    float* out = (float*)d_out;

    // ws: An 8 | Qb 8 | Kb 8 | Vb 8 | Ob 8 | 8 sq WtX 4 | gwT 4 | owT 2 | ctxb ~0.16  = ~50.2 MB
    // FF (8192x2048 bf16 = 32MB) aliases Qb..Ob. Residual Hf (fp32 16MB) lives in d_out.
    char* ws = (char*)d_ws;
    bf16* An = (bf16*)(ws);
    bf16* Qb = (bf16*)(ws + ((size_t)8<<20));
    bf16* Kb = (bf16*)(ws + ((size_t)16<<20));
    bf16* Vb = (bf16*)(ws + ((size_t)24<<20));
    bf16* Ob = (bf16*)(ws + ((size_t)32<<20));
    bf16* FF = Qb;
    float* Hf = out;
    bf16* WT = (bf16*)(ws + ((size_t)40<<20));   // 8 x 512KB square transposed weights
    bf16* wq1T = WT + 0*262144, *wk1T = WT + 1*262144, *wv1T = WT + 2*262144, *wo1T = WT + 3*262144;
    bf16* wq2T = WT + 4*262144, *wk2T = WT + 5*262144, *wv2T = WT + 6*262144, *wo2T = WT + 7*262144;
    bf16* gwT  = (bf16*)(ws + ((size_t)44<<20)); // [4096][512]
    bf16* owT  = (bf16*)(ws + ((size_t)48<<20)); // [512][2048]
    bf16* ctxb = (bf16*)(ws + ((size_t)50<<20)); // [154][512]

    dim3 blk(256);

    // ---- weight prep (same every call; graph-safe) ----
    TPtrs tp;
    tp.src[0]=wq1; tp.src[1]=wk1; tp.src[2]=wv1; tp.src[3]=wo1;
    tp.src[4]=wq2; tp.src[5]=wk2; tp.src[6]=wv2; tp.src[7]=wo2;
    tp.dst[0]=wq1T; tp.dst[1]=wk1T; tp.dst[2]=wv1T; tp.dst[3]=wo1T;
    tp.dst[4]=wq2T; tp.dst[5]=wk2T; tp.dst[6]=wv2T; tp.dst[7]=wo2T;
    transpose8_kernel<<<dim3(16,16,8), blk, 0, stream>>>(tp);
    transpose_bf16_kernel<<<dim3(128,16), blk, 0, stream>>>(gw, gwT, DIM, 4096);
    transpose_bf16_kernel<<<dim3(16,64), blk, 0, stream>>>(ow, owT, 2048, DIM);
    cast_bf16_kernel<<<dim3((NCTX*DIM+255)/256), blk, 0, stream>>>(ctx, ctxb, NCTX*DIM);

    dim3 gLN(NTOK/4);
    dim3 gGEMM(4, 64);        // N=512, M=8192
    dim3 gGEMMs(4, 2);        // N=512, M=154 (guarded)
    dim3 gGEGLU(32, 64);      // N=2048 (64/blk), M=8192
    dim3 gATT(SEQ/128, NHEAD, BATCH);

    // ---- self-attention ----
    ln_kernel<<<gLN, blk, 0, stream>>>(x, ln1g, ln1b, An, NTOK);
    gemm_mfma_kernel<0,bf16,false><<<gGEMM, blk, 0, stream>>>(An, wq1T, nullptr, nullptr, Qb, NTOK, DIM, DIM);
    gemm_mfma_kernel<0,bf16,false><<<gGEMM, blk, 0, stream>>>(An, wk1T, nullptr, nullptr, Kb, NTOK, DIM, DIM);
    gemm_mfma_kernel<0,bf16,false><<<gGEMM, blk, 0, stream>>>(An, wv1T, nullptr, nullptr, Vb, NTOK, DIM, DIM);
    attn_mfma_kernel<<<gATT, blk, 0, stream>>>(Qb, Kb, Vb, Ob, SEQ);
    gemm_mfma_kernel<1,float,false><<<gGEMM, blk, 0, stream>>>(Ob, wo1T, bo1, x, Hf, NTOK, DIM, DIM);

    // ---- cross-attention ----
    ln_kernel<<<gLN, blk, 0, stream>>>(Hf, ln2g, ln2b, An, NTOK);
    gemm_mfma_kernel<0,bf16,false><<<gGEMM, blk, 0, stream>>>(An, wq2T, nullptr, nullptr, Qb, NTOK, DIM, DIM);
    gemm_mfma_kernel<0,bf16,true><<<gGEMMs, blk, 0, stream>>>(ctxb, wk2T, nullptr, nullptr, Kb, NCTX, DIM, DIM);
    gemm_mfma_kernel<0,bf16,true><<<gGEMMs, blk, 0, stream>>>(ctxb, wv2T, nullptr, nullptr, Vb, NCTX, DIM, DIM);
    attn_mfma_kernel<<<gATT, blk, 0, stream>>>(Qb, Kb, Vb, Ob, CTXLEN);
    gemm_mfma_kernel<1,float,false><<<gGEMM, blk, 0, stream>>>(Ob, wo2T, bo2, Hf, Hf, NTOK, DIM, DIM);

    // ---- GEGLU FFN + output projection ----
    ln_kernel<<<gLN, blk, 0, stream>>>(Hf, ln3g, ln3b, An, NTOK);
    geglu_mfma_kernel<<<gGEGLU, blk, 0, stream>>>(An, gwT, gb, FF);
    gemm_mfma_kernel<1,float,false><<<gGEMM, blk, 0, stream>>>(FF, owT, ob, Hf, out, NTOK, DIM, 2048);
}

// Round 5
// 549.328 us; speedup vs baseline: 12.9263x; 1.3458x over previous
//
#include <hip/hip_runtime.h>
#include <hip/hip_bf16.h>
#include <math.h>

#define DIM 512
#define NHEAD 8
#define HD 64
#define BATCH 2
#define SEQ 4096
#define CTXLEN 77
#define NTOK (BATCH*SEQ)     // 8192
#define NCTX (BATCH*CTXLEN)  // 154

typedef __hip_bfloat16 bf16;
typedef __attribute__((ext_vector_type(8))) short bf8_t;   // 8 bf16 (4 VGPRs)
typedef __attribute__((ext_vector_type(4))) float f4_t;    // 4 fp32 acc

__device__ __forceinline__ float b2f(bf16 v){ return __bfloat162float(v); }
__device__ __forceinline__ bf16  f2b(float v){ return __float2bfloat16(v); }
__device__ __forceinline__ unsigned short f2bu(float v){ bf16 h = f2b(v); return *(unsigned short*)&h; }
__device__ __forceinline__ unsigned int packbf2(float a, float b){
    return (unsigned int)f2bu(a) | ((unsigned int)f2bu(b) << 16);
}
__device__ __forceinline__ void  stf(float* p, float v){ *p = v; }
__device__ __forceinline__ void  stf(bf16* p, float v){ *p = f2b(v); }

// ---------------- LayerNorm: one wave per row of 512; fp32 in, bf16 out ----------------
__global__ __launch_bounds__(256)
void ln_kernel(const float* __restrict__ x, const float* __restrict__ g,
               const float* __restrict__ b, bf16* __restrict__ out, int nrows)
{
    int row  = blockIdx.x * 4 + (threadIdx.x >> 6);
    int lane = threadIdx.x & 63;
    if (row >= nrows) return;
    const float* xr = x + (size_t)row * DIM;
    float v[8];
    float s = 0.f, sq = 0.f;
    #pragma unroll
    for (int j = 0; j < 8; ++j) {
        float f = xr[lane + 64*j];
        v[j] = f; s += f; sq += f*f;
    }
    #pragma unroll
    for (int off = 32; off; off >>= 1) {
        s  += __shfl_xor(s,  off);
        sq += __shfl_xor(sq, off);
    }
    float mean = s * (1.f/DIM);
    float var  = sq * (1.f/DIM) - mean*mean;
    float rstd = rsqrtf(var + 1e-5f);
    bf16* orow = out + (size_t)row * DIM;
    #pragma unroll
    for (int j = 0; j < 8; ++j) {
        int c = lane + 64*j;
        orow[c] = f2b((v[j]-mean)*rstd*g[c] + b[c]);
    }
}

// ---------------- weight prep ----------------
__global__ __launch_bounds__(256)
void transpose_bf16_kernel(const float* __restrict__ W, bf16* __restrict__ Wt, int K, int N)
{
    __shared__ float tile[32][33];
    int n0 = blockIdx.x * 32, k0 = blockIdx.y * 32;
    int tx = threadIdx.x & 31, ty = threadIdx.x >> 5;
    #pragma unroll
    for (int p = 0; p < 4; ++p)
        tile[ty + p*8][tx] = W[(size_t)(k0 + ty + p*8)*N + n0 + tx];
    __syncthreads();
    #pragma unroll
    for (int p = 0; p < 4; ++p)
        Wt[(size_t)(n0 + ty + p*8)*K + k0 + tx] = f2b(tile[tx][ty + p*8]);
}

struct TPtrs { const float* src[8]; bf16* dst[8]; };
__global__ __launch_bounds__(256)
void transpose8_kernel(TPtrs p)
{
    __shared__ float tile[32][33];
    const float* W = p.src[blockIdx.z];
    bf16* Wt = p.dst[blockIdx.z];
    int n0 = blockIdx.x * 32, k0 = blockIdx.y * 32;
    int tx = threadIdx.x & 31, ty = threadIdx.x >> 5;
    #pragma unroll
    for (int q = 0; q < 4; ++q)
        tile[ty + q*8][tx] = W[(size_t)(k0 + ty + q*8)*512 + n0 + tx];
    __syncthreads();
    #pragma unroll
    for (int q = 0; q < 4; ++q)
        Wt[(size_t)(n0 + ty + q*8)*512 + k0 + tx] = f2b(tile[tx][ty + q*8]);
}

__global__ __launch_bounds__(256)
void cast_bf16_kernel(const float* __restrict__ in, bf16* __restrict__ out, int n)
{
    int i = blockIdx.x*256 + threadIdx.x;
    if (i < n) out[i] = f2b(in[i]);
}

// ---------------- V transpose: V[b*T+tok][512] (head h cols) -> Vt[(b*8+h)*64+d][pitch] ----------------
// grid (pitch/64, 8, BATCH). Zero-pads toks >= T.
__global__ __launch_bounds__(256)
void v_transpose_kernel(const bf16* __restrict__ V, bf16* __restrict__ Vt, int T, int pitch)
{
    __shared__ __align__(16) unsigned short tile[64*64];
    const int tid = threadIdx.x;
    const int b = blockIdx.z, h = blockIdx.y;
    const int t0 = blockIdx.x * 64;
    #pragma unroll
    for (int it = 0; it < 2; ++it) {
        int e = tid + it*256;
        int t = e >> 3, c = e & 7;
        int gk = t0 + t;
        bf8_t v = {0,0,0,0,0,0,0,0};
        if (gk < T) v = *(const bf8_t*)(V + ((size_t)(b*T + gk))*DIM + h*HD + c*8);
        *(bf8_t*)&tile[t*64 + c*8] = v;
    }
    __syncthreads();
    #pragma unroll
    for (int it = 0; it < 2; ++it) {
        int e = tid + it*256;
        int d = e & 63, oc = e >> 6;   // oc 0..7 over both its (wave-uniform per instr)
        unsigned short tmp[8];
        #pragma unroll
        for (int j = 0; j < 8; ++j) tmp[j] = tile[(oc*8 + j)*64 + d];
        *(bf8_t*)(Vt + ((size_t)((b*8 + h)*64 + d))*pitch + t0 + oc*8) = *(bf8_t*)tmp;
    }
}

// ---------------- MFMA GEMM: C = A[MxK](bf16) @ Wt[NxK]^T (+bias)(+resid fp32) ----------------
// 128x64 tile, BK=64, 4 waves 2x2 (wave tile 64x32). Output buffers are 512-col;
// col block n0 selects outs.p[n0>>9] at local col n0&511 (lets one launch write Q/K/V).
struct OutPtrs { void* p[3]; };
template<int RESID, typename OUTT, bool GUARD>
__global__ __launch_bounds__(256)
void gemm_mfma_kernel(const bf16* __restrict__ A, const bf16* __restrict__ Wt,
                      const float* __restrict__ bias, const float* __restrict__ resid,
                      OutPtrs outs, int M, int K)
{
    __shared__ __align__(16) unsigned short As[128*64];
    __shared__ __align__(16) unsigned short Bs[64*64];
    const int tid  = threadIdx.x;
    const int wave = tid >> 6, lane = tid & 63;
    const int l16  = lane & 15, quad = lane >> 4;
    const int wm = (wave >> 1) * 64, wn = (wave & 1) * 32;
    const int m0 = blockIdx.y * 128, n0 = blockIdx.x * 64;
    OUTT* outp = (OUTT*)outs.p[n0 >> 9];
    const int lc0 = n0 & 511;

    f4_t acc[4][2];
    #pragma unroll
    for (int i = 0; i < 4; ++i) { acc[i][0] = f4_t{0,0,0,0}; acc[i][1] = f4_t{0,0,0,0}; }

    for (int k0 = 0; k0 < K; k0 += 64) {
        #pragma unroll
        for (int p = 0; p < 4; ++p) {
            int e = tid + p*256;
            int r = e >> 3, c = e & 7;
            int gr = m0 + r;
            if (GUARD) gr = (gr < M) ? gr : (M-1);
            bf8_t v = *(const bf8_t*)(A + (size_t)gr*K + k0 + c*8);
            *(bf8_t*)&As[r*64 + ((c ^ (r&7))*8)] = v;
        }
        #pragma unroll
        for (int p = 0; p < 2; ++p) {
            int e = tid + p*256;
            int r = e >> 3, c = e & 7;
            bf8_t v = *(const bf8_t*)(Wt + (size_t)(n0 + r)*K + k0 + c*8);
            *(bf8_t*)&Bs[r*64 + ((c ^ (r&7))*8)] = v;
        }
        __syncthreads();
        #pragma unroll
        for (int kc = 0; kc < 2; ++kc) {
            const int cg = kc*4 + quad;
            bf8_t af[4], bfr[2];
            #pragma unroll
            for (int mt = 0; mt < 4; ++mt) {
                int r = wm + mt*16 + l16;
                af[mt] = *(const bf8_t*)&As[r*64 + ((cg ^ (r&7))*8)];
            }
            #pragma unroll
            for (int nt = 0; nt < 2; ++nt) {
                int r = wn + nt*16 + l16;
                bfr[nt] = *(const bf8_t*)&Bs[r*64 + ((cg ^ (r&7))*8)];
            }
            #pragma unroll
            for (int mt = 0; mt < 4; ++mt)
                #pragma unroll
                for (int nt = 0; nt < 2; ++nt)
                    acc[mt][nt] = __builtin_amdgcn_mfma_f32_16x16x32_bf16(af[mt], bfr[nt], acc[mt][nt], 0, 0, 0);
        }
        __syncthreads();
    }

    #pragma unroll
    for (int mt = 0; mt < 4; ++mt) {
        #pragma unroll
        for (int r_ = 0; r_ < 4; ++r_) {
            int row = m0 + wm + mt*16 + quad*4 + r_;
            if (GUARD && row >= M) continue;
            size_t rb = (size_t)row * 512;
            #pragma unroll
            for (int nt = 0; nt < 2; ++nt) {
                int col = lc0 + wn + nt*16 + l16;
                float v = acc[mt][nt][r_];
                if (bias) v += bias[col];
                if (RESID) v += resid[rb + col];
                stf(&outp[rb + col], v);
            }
        }
    }
}

// ---------------- MFMA GEGLU (unchanged from R3) ----------------
__global__ __launch_bounds__(256)
void geglu_mfma_kernel(const bf16* __restrict__ A, const bf16* __restrict__ WtG,
                       const float* __restrict__ bias, bf16* __restrict__ outp)
{
    __shared__ __align__(16) unsigned short As[128*64];
    __shared__ __align__(16) unsigned short Bys[64*64];
    __shared__ __align__(16) unsigned short Bgs[64*64];
    const int tid  = threadIdx.x;
    const int wave = tid >> 6, lane = tid & 63;
    const int l16  = lane & 15, quad = lane >> 4;
    const int m0 = blockIdx.y * 128, n0 = blockIdx.x * 64;
    const int srow = tid >> 3, scol = tid & 7;

    f4_t accy[2][4], accg[2][4];
    #pragma unroll
    for (int i = 0; i < 2; ++i)
        #pragma unroll
        for (int j = 0; j < 4; ++j) { accy[i][j] = f4_t{0,0,0,0}; accg[i][j] = f4_t{0,0,0,0}; }

    for (int k0 = 0; k0 < DIM; k0 += 64) {
        #pragma unroll
        for (int p = 0; p < 4; ++p) {
            int r = srow + p*32;
            bf8_t v = *(const bf8_t*)(A + (size_t)(m0 + r)*DIM + k0 + scol*8);
            *(bf8_t*)&As[r*64 + ((scol ^ (r&7))*8)] = v;
        }
        #pragma unroll
        for (int p = 0; p < 2; ++p) {
            int r = srow + p*32;
            bf8_t vy = *(const bf8_t*)(WtG + (size_t)(n0 + r)*DIM + k0 + scol*8);
            bf8_t vg = *(const bf8_t*)(WtG + (size_t)(2048 + n0 + r)*DIM + k0 + scol*8);
            *(bf8_t*)&Bys[r*64 + ((scol ^ (r&7))*8)] = vy;
            *(bf8_t*)&Bgs[r*64 + ((scol ^ (r&7))*8)] = vg;
        }
        __syncthreads();
        #pragma unroll
        for (int kc = 0; kc < 2; ++kc) {
            const int cg = kc*4 + quad;
            bf8_t af[2];
            #pragma unroll
            for (int mt = 0; mt < 2; ++mt) {
                int r = wave*32 + mt*16 + l16;
                af[mt] = *(const bf8_t*)&As[r*64 + ((cg ^ (r&7))*8)];
            }
            #pragma unroll
            for (int nt = 0; nt < 4; ++nt) {
                int r = nt*16 + l16;
                bf8_t by = *(const bf8_t*)&Bys[r*64 + ((cg ^ (r&7))*8)];
                bf8_t bg = *(const bf8_t*)&Bgs[r*64 + ((cg ^ (r&7))*8)];
                #pragma unroll
                for (int mt = 0; mt < 2; ++mt) {
                    accy[mt][nt] = __builtin_amdgcn_mfma_f32_16x16x32_bf16(af[mt], by, accy[mt][nt], 0, 0, 0);
                    accg[mt][nt] = __builtin_amdgcn_mfma_f32_16x16x32_bf16(af[mt], bg, accg[mt][nt], 0, 0, 0);
                }
            }
        }
        __syncthreads();
    }

    #pragma unroll
    for (int mt = 0; mt < 2; ++mt) {
        #pragma unroll
        for (int r_ = 0; r_ < 4; ++r_) {
            int row = m0 + wave*32 + mt*16 + quad*4 + r_;
            size_t rb = (size_t)row * 2048;
            #pragma unroll
            for (int nt = 0; nt < 4; ++nt) {
                int col = n0 + nt*16 + l16;
                float y = accy[mt][nt][r_] + bias[col];
                float g = accg[mt][nt][r_] + bias[2048 + col];
                float t = tanhf(0.7978845608f*g*(1.f + 0.044715f*g*g));
                outp[rb + col] = f2b(y * 0.5f * g * (1.f + t));
            }
        }
    }
}

// ---------------- MFMA flash attention, transposed orientation ----------------
// 4 waves x 32 queries = 128 q/block, one (b,h). S^T = mfma(K-frag, Q-frag):
// col = query (= lane&15), rows = keys -> softmax is in-register (16 vals) + 2 shfls;
// m/l/alpha per-lane. O accumulated transposed (rows=d, cols=q). V pre-transposed
// in global (VtG), all LDS XOR-swizzled pitch-64 -> conflict-free b128.
__global__ __launch_bounds__(256)
void attn_mfma_kernel(const bf16* __restrict__ Qm, const bf16* __restrict__ Km,
                      const bf16* __restrict__ VtG, bf16* __restrict__ Om,
                      int T, int vpitch)
{
    __shared__ __align__(16) unsigned short Ks[64*64];
    __shared__ __align__(16) unsigned short Vts[64*64];
    __shared__ __align__(16) unsigned short Ps[4][16*64];

    const int tid  = threadIdx.x;
    const int wave = tid >> 6, lane = tid & 63;
    const int l16  = lane & 15, quad = lane >> 4;
    const int b = blockIdx.z, h = blockIdx.y;
    const int qblk = blockIdx.x * 128;

    // Q fragments (B-operand layout), pre-scaled by D^-0.5 = 0.125
    bf8_t qf[2][2];
    #pragma unroll
    for (int qn = 0; qn < 2; ++qn) {
        const bf16* qp = Qm + ((size_t)(b*SEQ + qblk + wave*32 + qn*16 + l16))*DIM + h*HD + quad*8;
        #pragma unroll
        for (int kc = 0; kc < 2; ++kc) {
            bf8_t v = *(const bf8_t*)(qp + kc*32);
            unsigned short* u = (unsigned short*)&v;
            #pragma unroll
            for (int j = 0; j < 8; ++j) {
                bf16 hv = *(bf16*)&u[j];
                u[j] = f2bu(b2f(hv) * 0.125f);
            }
            qf[qn][kc] = v;
        }
    }

    f4_t o[4][2];     // [d-tile][qn], transposed: rows=d, col=q
    #pragma unroll
    for (int dt = 0; dt < 4; ++dt) { o[dt][0] = f4_t{0,0,0,0}; o[dt][1] = f4_t{0,0,0,0}; }
    float m_run[2] = {-1e30f, -1e30f}, l_run[2] = {0.f, 0.f};

    const int ntiles = (T + 63) >> 6;
    for (int t0 = 0; t0 < ntiles; ++t0) {
        const int kb = t0 << 6;
        // ---- stage K and V^T (swizzled b128) ----
        #pragma unroll
        for (int it = 0; it < 2; ++it) {
            int e = tid + it*256;
            int r = e >> 3, c = e & 7;
            int gk = kb + r;
            bf8_t kv = {0,0,0,0,0,0,0,0};
            if (gk < T) kv = *(const bf8_t*)(Km + ((size_t)(b*T + gk))*DIM + h*HD + c*8);
            *(bf8_t*)&Ks[r*64 + ((c ^ (r&7))*8)] = kv;
            bf8_t vv = *(const bf8_t*)(VtG + ((size_t)((b*8 + h)*64 + r))*vpitch + kb + c*8);
            *(bf8_t*)&Vts[r*64 + ((c ^ (r&7))*8)] = vv;
        }
        __syncthreads();

        // ---- hoisted K and V fragments (A-operand layout) ----
        bf8_t kf[4][2], vf[4][2];
        #pragma unroll
        for (int t = 0; t < 4; ++t) {
            int r = t*16 + l16;
            #pragma unroll
            for (int kc = 0; kc < 2; ++kc) {
                int cg = kc*4 + quad;
                kf[t][kc] = *(const bf8_t*)&Ks[r*64 + ((cg ^ (r&7))*8)];
                vf[t][kc] = *(const bf8_t*)&Vts[r*64 + ((cg ^ (r&7))*8)];
            }
        }
        const bool tail = (kb + 64 > T);

        #pragma unroll
        for (int qn = 0; qn < 2; ++qn) {
            // ---- S^T tiles: sc[km] rows=keys km*16+quad*4+r, col=query l16 ----
            f4_t sc[4];
            #pragma unroll
            for (int km = 0; km < 4; ++km) {
                f4_t c = {0,0,0,0};
                c = __builtin_amdgcn_mfma_f32_16x16x32_bf16(kf[km][0], qf[qn][0], c, 0, 0, 0);
                c = __builtin_amdgcn_mfma_f32_16x16x32_bf16(kf[km][1], qf[qn][1], c, 0, 0, 0);
                sc[km] = c;
            }
            if (tail) {
                #pragma unroll
                for (int km = 0; km < 4; ++km)
                    #pragma unroll
                    for (int r = 0; r < 4; ++r)
                        if (kb + km*16 + quad*4 + r >= T) sc[km][r] = -1e30f;
            }
            // ---- in-register online softmax for query (qn,l16) ----
            float mx = sc[0][0];
            #pragma unroll
            for (int km = 0; km < 4; ++km)
                #pragma unroll
                for (int r = 0; r < 4; ++r) mx = fmaxf(mx, sc[km][r]);
            mx = fmaxf(mx, __shfl_xor(mx, 16));
            mx = fmaxf(mx, __shfl_xor(mx, 32));
            float mnew = fmaxf(m_run[qn], mx);
            float psum = 0.f;
            #pragma unroll
            for (int km = 0; km < 4; ++km)
                #pragma unroll
                for (int r = 0; r < 4; ++r) {
                    float p = __expf(sc[km][r] - mnew);
                    sc[km][r] = p; psum += p;
                }
            psum += __shfl_xor(psum, 16);
            psum += __shfl_xor(psum, 32);
            float alpha = __expf(m_run[qn] - mnew);
            m_run[qn] = mnew;
            l_run[qn] = l_run[qn]*alpha + psum;
            #pragma unroll
            for (int dt = 0; dt < 4; ++dt)
                #pragma unroll
                for (int r = 0; r < 4; ++r) o[dt][qn][r] *= alpha;
            // ---- P -> wave-private LDS (rows=query, cols=keys, swizzled) ----
            #pragma unroll
            for (int km = 0; km < 4; ++km) {
                uint2 w;
                w.x = packbf2(sc[km][0], sc[km][1]);
                w.y = packbf2(sc[km][2], sc[km][3]);
                int chunk = 2*km + (quad >> 1);
                int a = l16*64 + ((chunk ^ (l16 & 7))*8) + (quad & 1)*4;
                *(uint2*)&Ps[wave][a] = w;
            }
            // ---- PV: O^T += V-frag x P-frag ----
            #pragma unroll
            for (int kc = 0; kc < 2; ++kc) {
                int cg = kc*4 + quad;
                bf8_t pf = *(const bf8_t*)&Ps[wave][l16*64 + ((cg ^ (l16 & 7))*8)];
                #pragma unroll
                for (int dt = 0; dt < 4; ++dt)
                    o[dt][qn] = __builtin_amdgcn_mfma_f32_16x16x32_bf16(vf[dt][kc], pf, o[dt][qn], 0, 0, 0);
            }
        }
        __syncthreads();
    }

    // ---- epilogue: per-lane one query, 16 d-values; packed b64 stores ----
    #pragma unroll
    for (int qn = 0; qn < 2; ++qn) {
        float inv = 1.f / l_run[qn];
        int tok = qblk + wave*32 + qn*16 + l16;
        size_t base = ((size_t)(b*SEQ + tok))*DIM + h*HD;
        #pragma unroll
        for (int dt = 0; dt < 4; ++dt) {
            uint2 w;
            w.x = packbf2(o[dt][qn][0]*inv, o[dt][qn][1]*inv);
            w.y = packbf2(o[dt][qn][2]*inv, o[dt][qn][3]*inv);
            *(uint2*)(Om + base + dt*16 + quad*4) = w;
        }
    }
}

extern "C" void kernel_launch(void* const* d_in, const int* in_sizes, int n_in,
                              void* d_out, int out_size, void* d_ws, size_t ws_size,
                              hipStream_t stream)
{
    (void)in_sizes; (void)n_in; (void)out_size; (void)ws_size;
    const float* x    = (const float*)d_in[0];
    const float* ctx  = (const float*)d_in[1];
    const float* ln1g = (const float*)d_in[2];
    const float* ln1b = (const float*)d_in[3];
    const float* wq1  = (const float*)d_in[4];
    const float* wk1  = (const float*)d_in[5];
    const float* wv1  = (const float*)d_in[6];
    const float* wo1  = (const float*)d_in[7];
    const float* bo1  = (const float*)d_in[8];
    const float* ln2g = (const float*)d_in[9];
    const float* ln2b = (const float*)d_in[10];
    const float* wq2  = (const float*)d_in[11];
    const float* wk2  = (const float*)d_in[12];
    const float* wv2  = (const float*)d_in[13];
    const float* wo2  = (const float*)d_in[14];
    const float* bo2  = (const float*)d_in[15];
    const float* ln3g = (const float*)d_in[16];
    const float* ln3b = (const float*)d_in[17];
    const float* gw   = (const float*)d_in[18];
    const float* gb   = (const float*)d_in[19];
    const float* ow   = (const float*)d_in[20];
    const float* ob   = (const float*)d_in[21];
    float* out = (float*)d_out;

    // ws map (MB): 0 An/VtG(8) | 8 Qb(8) | 16 Kb(8) | 24 Vb(8) | 32 Ob(8) |
    //              40 WT(4) | 44 gwT(4) | 48 owT(2) | 50 ctxb(~0.16) | 50.5 VtG2(0.25)
    // FF (32MB) aliases Qb..Ob; VtG aliases An (An dead after QKV gemm, rewritten by ln2).
    // Residual Hf (fp32 16MB) lives in d_out.
    char* ws = (char*)d_ws;
    bf16* An  = (bf16*)(ws);
    bf16* VtG = (bf16*)(ws);                     // alias An
    bf16* Qb  = (bf16*)(ws + ((size_t)8<<20));
    bf16* Kb  = (bf16*)(ws + ((size_t)16<<20));
    bf16* Vb  = (bf16*)(ws + ((size_t)24<<20));
    bf16* Ob  = (bf16*)(ws + ((size_t)32<<20));
    bf16* FF  = Qb;
    float* Hf = out;
    bf16* WT  = (bf16*)(ws + ((size_t)40<<20));
    bf16* wq1T = WT + 0*262144, *wk1T = WT + 1*262144, *wv1T = WT + 2*262144, *wo1T = WT + 3*262144;
    bf16* wq2T = WT + 4*262144, *wk2T = WT + 5*262144, *wv2T = WT + 6*262144, *wo2T = WT + 7*262144;
    bf16* gwT  = (bf16*)(ws + ((size_t)44<<20));
    bf16* owT  = (bf16*)(ws + ((size_t)48<<20));
    bf16* ctxb = (bf16*)(ws + ((size_t)50<<20));
    bf16* VtG2 = (bf16*)(ws + ((size_t)50<<20) + ((size_t)512<<10));

    dim3 blk(256);

    // ---- weight prep ----
    TPtrs tp;
    tp.src[0]=wq1; tp.src[1]=wk1; tp.src[2]=wv1; tp.src[3]=wo1;
    tp.src[4]=wq2; tp.src[5]=wk2; tp.src[6]=wv2; tp.src[7]=wo2;
    tp.dst[0]=wq1T; tp.dst[1]=wk1T; tp.dst[2]=wv1T; tp.dst[3]=wo1T;
    tp.dst[4]=wq2T; tp.dst[5]=wk2T; tp.dst[6]=wv2T; tp.dst[7]=wo2T;
    transpose8_kernel<<<dim3(16,16,8), blk, 0, stream>>>(tp);
    transpose_bf16_kernel<<<dim3(128,16), blk, 0, stream>>>(gw, gwT, DIM, 4096);
    transpose_bf16_kernel<<<dim3(16,64), blk, 0, stream>>>(ow, owT, 2048, DIM);
    cast_bf16_kernel<<<dim3((NCTX*DIM+255)/256), blk, 0, stream>>>(ctx, ctxb, NCTX*DIM);

    dim3 gLN(NTOK/4);
    dim3 gQKV(24, 64);        // N=1536 -> Qb,Kb,Vb
    dim3 gG(8, 64);           // N=512
    dim3 gKVx(16, 2);         // N=1024, M=154 (guarded) -> Kb,Vb
    dim3 gGEGLU(32, 64);
    dim3 gATT(SEQ/128, NHEAD, BATCH);
    OutPtrs oQKV{{Qb, Kb, Vb}};
    OutPtrs oKVx{{Kb, Vb, nullptr}};
    OutPtrs oQ{{Qb, nullptr, nullptr}};
    OutPtrs oH{{Hf, nullptr, nullptr}};
    OutPtrs oOut{{out, nullptr, nullptr}};
    OutPtrs oOb{{Ob, nullptr, nullptr}};

    // ---- self-attention ----
    ln_kernel<<<gLN, blk, 0, stream>>>(x, ln1g, ln1b, An, NTOK);
    gemm_mfma_kernel<0,bf16,false><<<gQKV, blk, 0, stream>>>(An, wq1T, nullptr, nullptr, oQKV, NTOK, DIM);
    v_transpose_kernel<<<dim3(SEQ/64, NHEAD, BATCH), blk, 0, stream>>>(Vb, VtG, SEQ, SEQ);
    attn_mfma_kernel<<<gATT, blk, 0, stream>>>(Qb, Kb, VtG, Ob, SEQ, SEQ);
    gemm_mfma_kernel<1,float,false><<<gG, blk, 0, stream>>>(Ob, wo1T, bo1, x, oH, NTOK, DIM);

    // ---- cross-attention ----
    ln_kernel<<<gLN, blk, 0, stream>>>(Hf, ln2g, ln2b, An, NTOK);
    gemm_mfma_kernel<0,bf16,false><<<gG, blk, 0, stream>>>(An, wq2T, nullptr, nullptr, oQ, NTOK, DIM);
    gemm_mfma_kernel<0,bf16,true><<<gKVx, blk, 0, stream>>>(ctxb, wk2T, nullptr, nullptr, oKVx, NCTX, DIM);
    v_transpose_kernel<<<dim3(2, NHEAD, BATCH), blk, 0, stream>>>(Vb, VtG2, CTXLEN, 128);
    attn_mfma_kernel<<<gATT, blk, 0, stream>>>(Qb, Kb, VtG2, Ob, CTXLEN, 128);
    gemm_mfma_kernel<1,float,false><<<gG, blk, 0, stream>>>(Ob, wo2T, bo2, Hf, oH, NTOK, DIM);

    // ---- GEGLU FFN + output projection ----
    ln_kernel<<<gLN, blk, 0, stream>>>(Hf, ln3g, ln3b, An, NTOK);
    geglu_mfma_kernel<<<gGEGLU, blk, 0, stream>>>(An, gwT, gb, FF);
    gemm_mfma_kernel<1,float,false><<<gG, blk, 0, stream>>>(FF, owT, ob, Hf, oOut, NTOK, 2048);
}